// Round 1
// 89.235 us; speedup vs baseline: 1.0042x; 1.0042x over previous
//
#include <hip/hip_runtime.h>
#include <math.h>

// Problem constants (match reference)
#define NSEQ 64
#define TLEN 32768
#define G16_PER_SEQ 2048               // TLEN/16
#define NG16 (NSEQ * G16_PER_SEQ)      // 131072 level-16 groups
#define NTHREADS (NG16 * 4)            // 524288 threads, 4 gyro steps each
#define BLOCK 256
#define NBLOCKS (NTHREADS / BLOCK)     // 2048
#define N0 5
#define DT 0.01f
#define HUBER_INV 200.0f               // 1/0.005

// W*HUBER^2 = 25.  mean denominators: 64*2043*3 and 64*1019*3; level-32 extra 1/2.
__device__ __constant__ float C16 = 25.0f / (64.0f * 2043.0f * 3.0f);
__device__ __constant__ float C32 = 12.5f / (64.0f * 1019.0f * 3.0f);

// Quaternions q = {w, x, y, z}; R(q1)R(q2) = R(q1 o q2) (Hamilton product).
__device__ __forceinline__ void qmul(const float* a, const float* b, float* c) {
    c[0] = a[0] * b[0] - a[1] * b[1] - a[2] * b[2] - a[3] * b[3];
    c[1] = a[0] * b[1] + a[1] * b[0] + a[2] * b[3] - a[3] * b[2];
    c[2] = a[0] * b[2] + a[2] * b[0] + a[3] * b[1] - a[1] * b[3];
    c[3] = a[0] * b[3] + a[3] * b[0] + a[1] * b[2] - a[2] * b[1];
}

// exp(phi) as quat, small-angle series at half angle. |phi| <= ~0.06 here,
// so err ~1e-12: w = cos(a/2), k = sin(a/2)/a, v = k*phi.
__device__ __forceinline__ void qexp_small(float x, float y, float z, float* q) {
    float sq = x * x + y * y + z * z;                       // a^2
    float w = 1.0f - (sq * 0.125f) * (1.0f - sq * (1.0f / 48.0f));
    float k = 0.5f - (sq * (1.0f / 48.0f)) * (1.0f - sq * (1.0f / 80.0f));
    q[0] = w; q[1] = k * x; q[2] = k * y; q[3] = k * z;
}

// exp(phi) as quat, full range (xs angles up to ~6), matching reference branches.
__device__ __forceinline__ void qexp_full(float x, float y, float z, float* q) {
    float sq = x * x + y * y + z * z;
    float a = sqrtf(fmaxf(sq, 1e-16f));
    bool small = sq < 1e-12f;
    float sn, cs;
    __sincosf(0.5f * a, &sn, &cs);
    float w = small ? 1.0f - sq * 0.125f : cs;              // cos(a/2)
    float k = small ? 0.5f - sq * (1.0f / 48.0f) : sn / a;  // sin(a/2)/a
    q[0] = w; q[1] = k * x; q[2] = k * y; q[3] = k * z;
}

// huber-sum of log(R(o)^T R(x)) / HUBER via q_rel = conj(o) o x.
// cos(angle) = 2w^2-1 and vee = 4*w*v are both invariant under q -> -q,
// so this reproduces the reference's short-rotation acos branch exactly.
__device__ __forceinline__ float huber3_q(const float* o, const float* x) {
    float rw = o[0] * x[0] + o[1] * x[1] + o[2] * x[2] + o[3] * x[3];
    float rx = o[0] * x[1] - o[1] * x[0] - (o[2] * x[3] - o[3] * x[2]);
    float ry = o[0] * x[2] - o[2] * x[0] - (o[3] * x[1] - o[1] * x[3]);
    float rz = o[0] * x[3] - o[3] * x[0] - (o[1] * x[2] - o[2] * x[1]);
    float cosv = 2.0f * rw * rw - 1.0f;
    cosv = fminf(fmaxf(cosv, -1.0f + 1e-7f), 1.0f - 1e-7f);
    float angle = acosf(cosv);
    float sn = sqrtf(fmaxf(1.0f - cosv * cosv, 0.0f));      // sin(angle), in (0,pi)
    float f = (angle / (2.0f * sn)) * 4.0f * rw;            // sfac * 4w
    float v0 = f * rx, v1 = f * ry, v2 = f * rz;
    float acc = 0.0f;
#pragma unroll
    for (int t = 0; t < 3; ++t) {
        float zz = (t == 0 ? v0 : (t == 1 ? v1 : v2)) * HUBER_INV;
        float az = fabsf(zz);
        acc += (az < 1.0f) ? 0.5f * zz * zz : az - 0.5f;
    }
    return acc;
}

// Ordered non-commutative butterfly combine across lanes (xor mask).
// Lower lane holds earlier steps -> lower lane's quat multiplies on the left.
__device__ __forceinline__ void ordered_combine_q(float* q, int mask, bool upper) {
    float p[4], L[4], R[4], c[4];
#pragma unroll
    for (int t = 0; t < 4; ++t) {
        p[t] = __shfl_xor(q[t], mask);
        L[t] = upper ? p[t] : q[t];
        R[t] = upper ? q[t] : p[t];
    }
    qmul(L, R, c);
#pragma unroll
    for (int t = 0; t < 4; ++t) q[t] = c[t];
}

__global__ __launch_bounds__(256, 8) void gyro_loss_kernel(const float* __restrict__ xs,
                                                           const float* __restrict__ hat_xs,
                                                           float* __restrict__ partials) {
    const int tid = threadIdx.x;
    const int bid = blockIdx.x;
    const int gt = bid * BLOCK + tid;                 // global thread id
    const int g = gt >> 2;                            // level-16 group id

    // ---- issue ALL global loads up front so latency hides under the quat math ----
    // hat_xs slice for this thread: 12 consecutive floats (4 steps x 3), 3x float4.
    const float4* hp = reinterpret_cast<const float4*>(hat_xs) + (size_t)gt * 3;
    // xs for this group (quad lanes load the same float4 -> line broadcast).
    float4 xv = *(reinterpret_cast<const float4*>(xs) + (size_t)g * 12);
    float4 h0 = hp[0];
    float4 h1 = hp[1];
    float4 h2 = hp[2];

    // ---- product of this thread's 4 per-step rotations (tree, depth 2) ----
    float qa[4], qb[4], qp[4], qq[4], Om[4];
    qexp_small(DT * h0.x, DT * h0.y, DT * h0.z, qa);
    qexp_small(DT * h0.w, DT * h1.x, DT * h1.y, qb);
    qmul(qa, qb, qp);
    qexp_small(DT * h1.z, DT * h1.w, DT * h2.x, qa);
    qexp_small(DT * h2.y, DT * h2.z, DT * h2.w, qb);
    qmul(qa, qb, qq);
    qmul(qp, qq, Om);

    // ---- butterfly to the 16-step product (quad lanes; DPP shuffles) ----
    ordered_combine_q(Om, 1, (tid & 1) != 0);
    ordered_combine_q(Om, 2, (tid & 2) != 0);

    // ---- xs_r for this group ----
    float Xr[4];
    qexp_full(xv.x, xv.y, xv.z, Xr);

    // ---- level-16 term ----
    float partial = 0.0f;
    if ((tid & 3) == 0 && (g & (G16_PER_SEQ - 1)) >= N0)
        partial = C16 * huber3_q(Om, Xr);

    // ---- level 32: combine adjacent quads (xor 4) for both Om and Xr ----
    ordered_combine_q(Om, 4, (tid & 4) != 0);
    ordered_combine_q(Xr, 4, (tid & 4) != 0);
    if ((tid & 7) == 0 && ((g >> 1) & (G16_PER_SEQ / 2 - 1)) >= N0)
        partial += C32 * huber3_q(Om, Xr);

    // ---- block reduction -> plain store, no atomics/fences in the hot kernel ----
#pragma unroll
    for (int off = 32; off > 0; off >>= 1) partial += __shfl_down(partial, off);
    __shared__ float wsum[4];
    if ((tid & 63) == 0) wsum[tid >> 6] = partial;
    __syncthreads();
    if (tid == 0) partials[bid] = wsum[0] + wsum[1] + wsum[2] + wsum[3];
}

__global__ __launch_bounds__(256) void finish_kernel(const float* __restrict__ partials,
                                                     float* __restrict__ out) {
    const int tid = threadIdx.x;
    float s = 0.0f;
#pragma unroll
    for (int q = 0; q < NBLOCKS / 256; ++q) s += partials[q * 256 + tid];
#pragma unroll
    for (int off = 32; off > 0; off >>= 1) s += __shfl_down(s, off);
    __shared__ float wsum[4];
    if ((tid & 63) == 0) wsum[tid >> 6] = s;
    __syncthreads();
    if (tid == 0) out[0] = wsum[0] + wsum[1] + wsum[2] + wsum[3];
}

extern "C" void kernel_launch(void* const* d_in, const int* in_sizes, int n_in,
                              void* d_out, int out_size, void* d_ws, size_t ws_size,
                              hipStream_t stream) {
    const float* xs     = (const float*)d_in[0];
    // d_in[1] = dp, unused by the forward pass
    const float* hat_xs = (const float*)d_in[2];
    float* out = (float*)d_out;
    float* partials = (float*)d_ws;     // NBLOCKS floats, every one written before read

    gyro_loss_kernel<<<NBLOCKS, BLOCK, 0, stream>>>(xs, hat_xs, partials);
    finish_kernel<<<1, 256, 0, stream>>>(partials, out);
}